// Round 5
// baseline (3090.579 us; speedup 1.0000x reference)
//
#include <hip/hip_runtime.h>

#define HW_ (256 * 256)

typedef float v2f __attribute__((ext_vector_type(2)));

// Compare-exchange helpers (all compile-time indices -> registers)
#define CE_ASC(arr, i, l)                    \
  {                                          \
    const float _a = arr[i], _b = arr[l];    \
    arr[i] = fminf(_a, _b);                  \
    arr[l] = fmaxf(_a, _b);                  \
  }
#define CE_DESC(arr, i, l)                   \
  {                                          \
    const float _a = arr[i], _b = arr[l];    \
    arr[i] = fmaxf(_a, _b);                  \
    arr[l] = fminf(_a, _b);                  \
  }

// One wave (64 threads) handles one (window, head) unit.
// Block = 256 threads = 4 units sharing the same (b, h, wn), wm = 4 consecutive.
// Thread t = query row (token) within the window; s[64] = its score row.
__global__ __launch_bounds__(256, 4)
void slice_attn_kernel(const float* __restrict__ Q,
                       const float* __restrict__ K,
                       const float* __restrict__ V,
                       const float* __restrict__ RT,
                       float* __restrict__ O) {
  // [unit][quad][kt][4] layout: staging writes are 8-way (not 32-way) bank
  // conflicted; score/PV reads stay 4x wave-uniform ds_read_b128 per row.
  __shared__ __align__(16) float k_lds[4][1024];
  __shared__ __align__(16) float v_lds[4][1024];
  __shared__ float bias_lds[225];  // rel-pos column for this head

  const int tid  = threadIdx.x;
  const int wave = tid >> 6;
  const int t    = tid & 63;
  const int bid  = blockIdx.x;

  // decode (b, h, wn, wm) with wm innermost for L2 locality
  const int wm = ((bid & 7) << 2) | wave;
  const int wn = (bid >> 3) & 31;
  const int h  = (bid >> 8) & 7;
  const int b  = bid >> 11;

  if (tid < 225) bias_lds[tid] = RT[tid * 8 + h];

  const int sh = t >> 3, sw = t & 7;
  const int y  = wn * 8 + sh;
  const int x  = wm * 8 + sw;
  const int xs = (x - 4) & 255;  // rolled-right-by-4 source column (wraps at wm==0)

  const int base = (b * 128 + h * 16) * HW_;
  const float* qp = Q + base + y * 256 + x;
  const float* kp = K + base + y * 256 + xs;
  const float* vp = V + base + y * 256 + xs;

  float* kl = k_lds[wave];
  float* vl = v_lds[wave];

  v2f qv[8];
  #pragma unroll
  for (int q4 = 0; q4 < 4; ++q4) {
    float4 kv, vv;
    kv.x = kp[(q4 * 4 + 0) * HW_];
    kv.y = kp[(q4 * 4 + 1) * HW_];
    kv.z = kp[(q4 * 4 + 2) * HW_];
    kv.w = kp[(q4 * 4 + 3) * HW_];
    vv.x = vp[(q4 * 4 + 0) * HW_];
    vv.y = vp[(q4 * 4 + 1) * HW_];
    vv.z = vp[(q4 * 4 + 2) * HW_];
    vv.w = vp[(q4 * 4 + 3) * HW_];
    *reinterpret_cast<float4*>(kl + q4 * 256 + t * 4) = kv;
    *reinterpret_cast<float4*>(vl + q4 * 256 + t * 4) = vv;
    // q * SCALE (0.25 is a power of 2 -> exact)
    qv[2 * q4 + 0].x = qp[(q4 * 4 + 0) * HW_] * 0.25f;
    qv[2 * q4 + 0].y = qp[(q4 * 4 + 1) * HW_] * 0.25f;
    qv[2 * q4 + 1].x = qp[(q4 * 4 + 2) * HW_] * 0.25f;
    qv[2 * q4 + 1].y = qp[(q4 * 4 + 3) * HW_] * 0.25f;
  }
  __syncthreads();

  // ---- scores: bit-replicate numpy einsum's f32 sum-of-products
  //      (4-lane SSE accumulator, NO fma, lane_j = ((p_j+p_{j+4})+p_{j+8})+p_{j+12},
  //       horizontal (L0+L1)+(L2+L3)). Packed v2f ops are IEEE per-lane, so the
  //       tree is preserved; contract(off) prevents mul+add fusion.
  float s[64];
  {
    #pragma clang fp contract(off)
    #pragma unroll
    for (int kt = 0; kt < 64; ++kt) {
      const float4 kq0 = *reinterpret_cast<const float4*>(kl + 0 * 256 + kt * 4);
      const float4 kq1 = *reinterpret_cast<const float4*>(kl + 1 * 256 + kt * 4);
      const float4 kq2 = *reinterpret_cast<const float4*>(kl + 2 * 256 + kt * 4);
      const float4 kq3 = *reinterpret_cast<const float4*>(kl + 3 * 256 + kt * 4);
      const v2f P0 = qv[0] * (v2f){kq0.x, kq0.y};   // (p0,p1)
      const v2f P1 = qv[1] * (v2f){kq0.z, kq0.w};   // (p2,p3)
      const v2f P2 = qv[2] * (v2f){kq1.x, kq1.y};   // (p4,p5)
      const v2f P3 = qv[3] * (v2f){kq1.z, kq1.w};   // (p6,p7)
      const v2f P4 = qv[4] * (v2f){kq2.x, kq2.y};   // (p8,p9)
      const v2f P5 = qv[5] * (v2f){kq2.z, kq2.w};   // (p10,p11)
      const v2f P6 = qv[6] * (v2f){kq3.x, kq3.y};   // (p12,p13)
      const v2f P7 = qv[7] * (v2f){kq3.z, kq3.w};   // (p14,p15)
      const v2f L01 = ((P0 + P2) + P4) + P6;        // (L0,L1)
      const v2f L23 = ((P1 + P3) + P5) + P7;        // (L2,L3)
      s[kt] = (L01.x + L01.y) + (L23.x + L23.y);
    }
  }

  // ---- top-16 threshold: 4x bitonic sort16 (ascending) on copies,
  //      2x top-16 merge, closed-form 16th-largest of two sorted-16s.
  float A[16], Btop[16];
  {
    float c1[16], c2[16];
    #pragma unroll
    for (int i = 0; i < 16; ++i) { c1[i] = s[i]; c2[i] = s[i + 16]; }
    // sort16 ascending (standard bitonic network)
    #pragma unroll
    for (int k = 2; k <= 16; k <<= 1) {
      #pragma unroll
      for (int j = k >> 1; j > 0; j >>= 1) {
        #pragma unroll
        for (int i = 0; i < 16; ++i) {
          const int l = i ^ j;
          if (l > i) {
            if ((i & k) == 0) { CE_ASC(c1, i, l); CE_DESC(c1, i, l); }  // placeholder
          }
        }
      }
    }
    // (the loop above is replaced below by explicit networks; see SORT16)
    (void)c1; (void)c2;
  }

  // Explicit sort16-asc applied to four chunks + merges.
  {
    float Z[32];

    // --- chunk pair 1: s[0..15], s[16..31] -> A (top16 asc of first 32)
    #pragma unroll
    for (int i = 0; i < 16; ++i) Z[i] = s[i];
    #pragma unroll
    for (int k = 2; k <= 16; k <<= 1)
      #pragma unroll
      for (int j = k >> 1; j > 0; j >>= 1)
        #pragma unroll
        for (int i = 0; i < 16; ++i) {
          const int l = i ^ j;
          if (l > i) {
            if ((i & k) == 0) { CE_ASC(Z, i, l) } else { CE_DESC(Z, i, l) }
          }
        }
    #pragma unroll
    for (int i = 0; i < 16; ++i) Z[16 + i] = s[16 + i];
    #pragma unroll
    for (int k = 2; k <= 16; k <<= 1)
      #pragma unroll
      for (int j = k >> 1; j > 0; j >>= 1)
        #pragma unroll
        for (int i = 0; i < 16; ++i) {
          const int l = i ^ j;
          if (l > i) {
            if ((i & k) == 0) { CE_ASC(Z, 16 + i, 16 + l) } else { CE_DESC(Z, 16 + i, 16 + l) }
          }
        }
    // bitonic concat: reverse second half -> [asc, desc] is bitonic
    #pragma unroll
    for (int i = 0; i < 8; ++i) {
      const float tmp = Z[16 + i]; Z[16 + i] = Z[31 - i]; Z[31 - i] = tmp;
    }
    // half-cleaner: high half gets the 16 largest
    #pragma unroll
    for (int i = 0; i < 16; ++i) CE_ASC(Z, i, i + 16)
    // ascending bitonic merge of high half
    #pragma unroll
    for (int j = 8; j > 0; j >>= 1)
      #pragma unroll
      for (int i = 16; i < 32; ++i) {
        const int l = i ^ j;
        if (l > i) CE_ASC(Z, i, l)
      }
    #pragma unroll
    for (int i = 0; i < 16; ++i) A[i] = Z[16 + i];

    // --- chunk pair 2: s[32..47], s[48..63] -> Btop
    #pragma unroll
    for (int i = 0; i < 16; ++i) Z[i] = s[32 + i];
    #pragma unroll
    for (int k = 2; k <= 16; k <<= 1)
      #pragma unroll
      for (int j = k >> 1; j > 0; j >>= 1)
        #pragma unroll
        for (int i = 0; i < 16; ++i) {
          const int l = i ^ j;
          if (l > i) {
            if ((i & k) == 0) { CE_ASC(Z, i, l) } else { CE_DESC(Z, i, l) }
          }
        }
    #pragma unroll
    for (int i = 0; i < 16; ++i) Z[16 + i] = s[48 + i];
    #pragma unroll
    for (int k = 2; k <= 16; k <<= 1)
      #pragma unroll
      for (int j = k >> 1; j > 0; j >>= 1)
        #pragma unroll
        for (int i = 0; i < 16; ++i) {
          const int l = i ^ j;
          if (l > i) {
            if ((i & k) == 0) { CE_ASC(Z, 16 + i, 16 + l) } else { CE_DESC(Z, 16 + i, 16 + l) }
          }
        }
    #pragma unroll
    for (int i = 0; i < 8; ++i) {
      const float tmp = Z[16 + i]; Z[16 + i] = Z[31 - i]; Z[31 - i] = tmp;
    }
    #pragma unroll
    for (int i = 0; i < 16; ++i) CE_ASC(Z, i, i + 16)
    #pragma unroll
    for (int j = 8; j > 0; j >>= 1)
      #pragma unroll
      for (int i = 16; i < 32; ++i) {
        const int l = i ^ j;
        if (l > i) CE_ASC(Z, i, l)
      }
    #pragma unroll
    for (int i = 0; i < 16; ++i) Btop[i] = Z[16 + i];
  }

  // closed-form 16th largest of A ∪ Btop (both ascending, 16 each):
  // thr = max( B[0], A[0], max_{i=1..15} min(A[16-i], B[i]) )
  float thr = fmaxf(A[0], Btop[0]);
  #pragma unroll
  for (int i = 1; i < 16; ++i) thr = fmaxf(thr, fminf(A[16 - i], Btop[i]));
  const float m = fmaxf(A[15], Btop[15]);  // pre-bias max (bias small: safe shift)

  // ---- count strictly-greater (for top_k tie semantics)
  int cgt = 0;
  #pragma unroll
  for (int i = 0; i < 64; ++i) cgt += (s[i] > thr) ? 1 : 0;

  // ---- fused: selection (index-ordered tie quota) + bias + exp + denom + PV
  const int vbase = sh * 15 + sw;  // ridx = vbase + (112 - kh*15 - kw), >= 0
  const float* bp = &bias_lds[vbase];
  const bool edge = (wm == 0);

  v2f av[8];
  #pragma unroll
  for (int j = 0; j < 8; ++j) av[j] = (v2f){0.0f, 0.0f};
  float d0 = 0.0f, d1 = 0.0f;
  int cnt = cgt;
  #pragma unroll
  for (int i = 0; i < 64; ++i) {
    const float sv = s[i];
    const bool eq   = (sv == thr);
    bool take = (sv > thr) || (eq && (cnt < 16));
    cnt += eq ? 1 : 0;
    if (edge && (i & 7) < 4) take = false;  // post-softmax column mask
    const float bv = bp[112 - (i >> 3) * 15 - (i & 7)];
    const float p  = __expf(sv + bv - m);
    if (i & 1) d1 += p; else d0 += p;       // denominator over ALL 64
    const float w = take ? p : 0.0f;
    const v2f w2 = (v2f){w, w};
    const float4 vq0 = *reinterpret_cast<const float4*>(vl + 0 * 256 + i * 4);
    const float4 vq1 = *reinterpret_cast<const float4*>(vl + 1 * 256 + i * 4);
    const float4 vq2 = *reinterpret_cast<const float4*>(vl + 2 * 256 + i * 4);
    const float4 vq3 = *reinterpret_cast<const float4*>(vl + 3 * 256 + i * 4);
    av[0] += w2 * (v2f){vq0.x, vq0.y};
    av[1] += w2 * (v2f){vq0.z, vq0.w};
    av[2] += w2 * (v2f){vq1.x, vq1.y};
    av[3] += w2 * (v2f){vq1.z, vq1.w};
    av[4] += w2 * (v2f){vq2.x, vq2.y};
    av[5] += w2 * (v2f){vq2.z, vq2.w};
    av[6] += w2 * (v2f){vq3.x, vq3.y};
    av[7] += w2 * (v2f){vq3.z, vq3.w};
  }
  const float inv = 1.0f / (d0 + d1);
  const v2f inv2 = (v2f){inv, inv};
  #pragma unroll
  for (int j = 0; j < 8; ++j) av[j] *= inv2;

  // ---- store (channel cc = 2j / 2j+1)
  float* op = O + base + y * 256 + x;
  #pragma unroll
  for (int j = 0; j < 8; ++j) {
    op[(2 * j + 0) * HW_] = av[j].x;
    op[(2 * j + 1) * HW_] = av[j].y;
  }
}

extern "C" void kernel_launch(void* const* d_in, const int* in_sizes, int n_in,
                              void* d_out, int out_size, void* d_ws, size_t ws_size,
                              hipStream_t stream) {
  const float* Q  = (const float*)d_in[0];
  const float* K  = (const float*)d_in[1];
  const float* V  = (const float*)d_in[2];
  const float* RT = (const float*)d_in[3];
  float* O = (float*)d_out;
  dim3 grid(4096), block(256);
  hipLaunchKernelGGL(slice_attn_kernel, grid, block, 0, stream, Q, K, V, RT, O);
}

// Round 6
// 1916.428 us; speedup vs baseline: 1.6127x; 1.6127x over previous
//
#include <hip/hip_runtime.h>

#define HW_ (256 * 256)

typedef float v2f __attribute__((ext_vector_type(2)));

#define CE_ASC(arr, i, l)                  \
  {                                        \
    const float _a = arr[i], _b = arr[l];  \
    arr[i] = fminf(_a, _b);                \
    arr[l] = fmaxf(_a, _b);                \
  }
#define CE_DESC(arr, i, l)                 \
  {                                        \
    const float _a = arr[i], _b = arr[l];  \
    arr[i] = fmaxf(_a, _b);                \
    arr[l] = fminf(_a, _b);                \
  }

// One wave (64 threads) handles one (window, head) unit.
// Block = 256 threads = 4 units sharing the same (b, h, wn), wm = 4 consecutive.
// Thread t = query row (token) within the window; s[64] = its score row
// (static indexing only -> register file; allocator parks it in AGPRs).
__global__ __launch_bounds__(256, 3)
void slice_attn_kernel(const float* __restrict__ Q,
                       const float* __restrict__ K,
                       const float* __restrict__ V,
                       const float* __restrict__ RT,
                       float* __restrict__ O) {
  // [unit][quad][kt][4] layout: staging writes at the 8-clk wave64-b128 BW
  // floor (not 32-way conflicted); reads are wave-uniform broadcasts (free).
  __shared__ __align__(16) float k_lds[4][1024];
  __shared__ __align__(16) float v_lds[4][1024];
  __shared__ float bias_lds[225];  // rel-pos column for this head

  const int tid  = threadIdx.x;
  const int wave = tid >> 6;
  const int t    = tid & 63;
  const int bid  = blockIdx.x;

  // decode (b, h, wn, wm) with wm innermost for L2 locality
  const int wm = ((bid & 7) << 2) | wave;
  const int wn = (bid >> 3) & 31;
  const int h  = (bid >> 8) & 7;
  const int b  = bid >> 11;

  if (tid < 225) bias_lds[tid] = RT[tid * 8 + h];

  const int sh = t >> 3, sw = t & 7;
  const int y  = wn * 8 + sh;
  const int x  = wm * 8 + sw;
  const int xs = (x - 4) & 255;  // rolled-right-by-4 source column (wraps at wm==0)

  const int base = (b * 128 + h * 16) * HW_;
  const float* qp = Q + base + y * 256 + x;
  const float* kp = K + base + y * 256 + xs;
  const float* vp = V + base + y * 256 + xs;

  float* kl = k_lds[wave];
  float* vl = v_lds[wave];

  v2f qv[8];
  #pragma unroll
  for (int q4 = 0; q4 < 4; ++q4) {
    float4 kv, vv;
    kv.x = kp[(q4 * 4 + 0) * HW_];
    kv.y = kp[(q4 * 4 + 1) * HW_];
    kv.z = kp[(q4 * 4 + 2) * HW_];
    kv.w = kp[(q4 * 4 + 3) * HW_];
    vv.x = vp[(q4 * 4 + 0) * HW_];
    vv.y = vp[(q4 * 4 + 1) * HW_];
    vv.z = vp[(q4 * 4 + 2) * HW_];
    vv.w = vp[(q4 * 4 + 3) * HW_];
    *reinterpret_cast<float4*>(kl + q4 * 256 + t * 4) = kv;
    *reinterpret_cast<float4*>(vl + q4 * 256 + t * 4) = vv;
    // q * SCALE (0.25 is a power of 2 -> exact)
    qv[2 * q4 + 0].x = qp[(q4 * 4 + 0) * HW_] * 0.25f;
    qv[2 * q4 + 0].y = qp[(q4 * 4 + 1) * HW_] * 0.25f;
    qv[2 * q4 + 1].x = qp[(q4 * 4 + 2) * HW_] * 0.25f;
    qv[2 * q4 + 1].y = qp[(q4 * 4 + 3) * HW_] * 0.25f;
  }
  __syncthreads();

  // ---- chunked scores (np-einsum-bit-exact tree) + streaming top-16.
  //      Scores: 4-lane SSE accumulator, NO fma,
  //      lane_j = ((p_j+p_{j+4})+p_{j+8})+p_{j+12}, horizontal (L0+L1)+(L2+L3).
  //      Per 16-chunk: stash to s[], bitonic-sort16 the chunk copy, merge into
  //      running ascending top-16 A (half-cleaner + bitonic merge).
  float s[64];
  float A[16];
  {
    #pragma clang fp contract(off)
    #pragma unroll
    for (int c4 = 0; c4 < 4; ++c4) {
      float c[16];
      #pragma unroll
      for (int kk = 0; kk < 16; ++kk) {
        const int kt = c4 * 16 + kk;
        const float4 kq0 = *reinterpret_cast<const float4*>(kl + 0 * 256 + kt * 4);
        const float4 kq1 = *reinterpret_cast<const float4*>(kl + 1 * 256 + kt * 4);
        const float4 kq2 = *reinterpret_cast<const float4*>(kl + 2 * 256 + kt * 4);
        const float4 kq3 = *reinterpret_cast<const float4*>(kl + 3 * 256 + kt * 4);
        const v2f P0 = qv[0] * (v2f){kq0.x, kq0.y};   // (p0,p1)
        const v2f P1 = qv[1] * (v2f){kq0.z, kq0.w};   // (p2,p3)
        const v2f P2 = qv[2] * (v2f){kq1.x, kq1.y};   // (p4,p5)
        const v2f P3 = qv[3] * (v2f){kq1.z, kq1.w};   // (p6,p7)
        const v2f P4 = qv[4] * (v2f){kq2.x, kq2.y};   // (p8,p9)
        const v2f P5 = qv[5] * (v2f){kq2.z, kq2.w};   // (p10,p11)
        const v2f P6 = qv[6] * (v2f){kq3.x, kq3.y};   // (p12,p13)
        const v2f P7 = qv[7] * (v2f){kq3.z, kq3.w};   // (p14,p15)
        const v2f L01 = ((P0 + P2) + P4) + P6;        // (L0,L1)
        const v2f L23 = ((P1 + P3) + P5) + P7;        // (L2,L3)
        const float val = (L01.x + L01.y) + (L23.x + L23.y);
        c[kk] = val;
        s[kt] = val;
      }
      // bitonic sort16 ascending (80 CE, all compile-time indices)
      #pragma unroll
      for (int k = 2; k <= 16; k <<= 1) {
        #pragma unroll
        for (int j = k >> 1; j > 0; j >>= 1) {
          #pragma unroll
          for (int i = 0; i < 16; ++i) {
            const int l = i ^ j;
            if (l > i) {
              if ((i & k) == 0) { CE_ASC(c, i, l) } else { CE_DESC(c, i, l) }
            }
          }
        }
      }
      if (c4 == 0) {
        #pragma unroll
        for (int i = 0; i < 16; ++i) A[i] = c[i];
      } else {
        // top-16 of (A asc) U (c asc): half-cleaner against reversed c,
        // result is bitonic; bitonic-merge it back to ascending.
        float hm[16];
        #pragma unroll
        for (int i = 0; i < 16; ++i) hm[i] = fmaxf(A[i], c[15 - i]);
        #pragma unroll
        for (int j = 8; j > 0; j >>= 1) {
          #pragma unroll
          for (int i = 0; i < 16; ++i) {
            const int l = i ^ j;
            if (l > i) CE_ASC(hm, i, l)
          }
        }
        #pragma unroll
        for (int i = 0; i < 16; ++i) A[i] = hm[i];
      }
    }
  }

  const float thr = A[0];   // 16th largest (exact value from the score set)
  const float m   = A[15];  // pre-bias max (bias |.|<=~0.1 -> safe shift)
  // strictly-greater count: all >thr values are inside the top-16
  int cgt = 0;
  #pragma unroll
  for (int i = 1; i < 16; ++i) cgt += (A[i] > thr) ? 1 : 0;

  // ---- fused: selection (index-ordered tie quota) + bias + exp + denom + PV
  const int vbase = sh * 15 + sw;  // ridx = vbase + (112 - kh*15 - kw), in [0,224]
  const float* bp = &bias_lds[vbase];
  const bool edge = (wm == 0);

  v2f av[8];
  #pragma unroll
  for (int j = 0; j < 8; ++j) av[j] = (v2f){0.0f, 0.0f};
  float d0 = 0.0f, d1 = 0.0f;
  int cnt = cgt;
  #pragma unroll
  for (int i = 0; i < 64; ++i) {
    const float sv = s[i];
    const bool eq = (sv == thr);
    bool take = (sv > thr) || (eq && (cnt < 16));
    cnt += eq ? 1 : 0;
    if (edge && (i & 7) < 4) take = false;  // post-softmax column mask
    const float bv = bp[112 - (i >> 3) * 15 - (i & 7)];
    const float p  = __expf(sv + bv - m);
    if (i & 1) d1 += p; else d0 += p;       // denominator over ALL 64
    const float w = take ? p : 0.0f;
    const v2f w2 = (v2f){w, w};
    const float4 vq0 = *reinterpret_cast<const float4*>(vl + 0 * 256 + i * 4);
    const float4 vq1 = *reinterpret_cast<const float4*>(vl + 1 * 256 + i * 4);
    const float4 vq2 = *reinterpret_cast<const float4*>(vl + 2 * 256 + i * 4);
    const float4 vq3 = *reinterpret_cast<const float4*>(vl + 3 * 256 + i * 4);
    av[0] += w2 * (v2f){vq0.x, vq0.y};
    av[1] += w2 * (v2f){vq0.z, vq0.w};
    av[2] += w2 * (v2f){vq1.x, vq1.y};
    av[3] += w2 * (v2f){vq1.z, vq1.w};
    av[4] += w2 * (v2f){vq2.x, vq2.y};
    av[5] += w2 * (v2f){vq2.z, vq2.w};
    av[6] += w2 * (v2f){vq3.x, vq3.y};
    av[7] += w2 * (v2f){vq3.z, vq3.w};
  }
  const float inv = 1.0f / (d0 + d1);
  const v2f inv2 = (v2f){inv, inv};
  #pragma unroll
  for (int j = 0; j < 8; ++j) av[j] *= inv2;

  // ---- store (channel cc = 2j / 2j+1)
  float* op = O + base + y * 256 + x;
  #pragma unroll
  for (int j = 0; j < 8; ++j) {
    op[(2 * j + 0) * HW_] = av[j].x;
    op[(2 * j + 1) * HW_] = av[j].y;
  }
}

extern "C" void kernel_launch(void* const* d_in, const int* in_sizes, int n_in,
                              void* d_out, int out_size, void* d_ws, size_t ws_size,
                              hipStream_t stream) {
  const float* Q  = (const float*)d_in[0];
  const float* K  = (const float*)d_in[1];
  const float* V  = (const float*)d_in[2];
  const float* RT = (const float*)d_in[3];
  float* O = (float*)d_out;
  dim3 grid(4096), block(256);
  hipLaunchKernelGGL(slice_attn_kernel, grid, block, 0, stream, Q, K, V, RT, O);
}